// Round 8
// baseline (586.297 us; speedup 1.0000x reference)
//
#include <hip/hip_runtime.h>
#include <math.h>

// GCN 2-layer forward, MI355X. Round 15: r12 pipeline + src-deletion +
// atomic-CSR preprocessing. r14 lesson: never fuse heterogeneous roles into
// one kernel (worst-case VGPR/LDS allocation throttles all roles; k_super 91us
// @ 20% occ). Separate kernels, each with its own allocation:
//  - k_chist: edge stream -> global srcCnt/dstCnt atomics + coarse bCntD;
//    weight convert + dropout-mask blocks appended (uniform small alloc).
//  - k_scan (98 blks): off/norm_dst from bCntD prefix + dstCnt scan (old fine
//    minus both LDS-atomic passes, minus pd).
//  - k_scatter (1024 blks): csr[off[d]+atomicAdd(cur0[d],1)] = s. pd deleted.
//  - k_gemm1: r12 standalone + srcCnt rsqrt.
//  - k_gather1: r14 version verbatim (measured 90.2us, VGPR 36).
//  - k_gather2: r12 verbatim.

#define NF0 256
#define NF1 128
#define NC  47
#define CB  1024
typedef __attribute__((ext_vector_type(8))) short bfrag;
typedef __attribute__((ext_vector_type(4))) float f32x4;

__device__ __forceinline__ unsigned short f2bf(float f) {   // RNE
  unsigned u = __float_as_uint(f);
  return (unsigned short)((u + 0x7fffu + ((u >> 16) & 1u)) >> 16);
}
__device__ __forceinline__ unsigned pack2bf(float a, float b) {
  return (unsigned)f2bf(a) | ((unsigned)f2bf(b) << 16);
}
__device__ __forceinline__ float bflo(unsigned v) { return __uint_as_float(v << 16); }
__device__ __forceinline__ float bfhi(unsigned v) { return __uint_as_float(v & 0xffff0000u); }

// ---------------- threefry2x32 (verified r1/r2) ------------
__device__ __forceinline__ unsigned rotl_(unsigned x, int n) {
  return (x << n) | (x >> (32 - n));
}
__device__ __forceinline__ void threefry2x32_(unsigned x0, unsigned x1,
                                              unsigned& o0, unsigned& o1) {
  const unsigned k0 = 0u, k1 = 42u;
  const unsigned k2 = k0 ^ k1 ^ 0x1BD11BDAu;
  x0 += k0; x1 += k1;
  x0+=x1; x1=rotl_(x1,13); x1^=x0;
  x0+=x1; x1=rotl_(x1,15); x1^=x0;
  x0+=x1; x1=rotl_(x1,26); x1^=x0;
  x0+=x1; x1=rotl_(x1, 6); x1^=x0;
  x0+=k1; x1+=k2+1u;
  x0+=x1; x1=rotl_(x1,17); x1^=x0;
  x0+=x1; x1=rotl_(x1,29); x1^=x0;
  x0+=x1; x1=rotl_(x1,16); x1^=x0;
  x0+=x1; x1=rotl_(x1,24); x1^=x0;
  x0+=k2; x1+=k0+2u;
  x0+=x1; x1=rotl_(x1,13); x1^=x0;
  x0+=x1; x1=rotl_(x1,15); x1^=x0;
  x0+=x1; x1=rotl_(x1,26); x1^=x0;
  x0+=x1; x1=rotl_(x1, 6); x1^=x0;
  x0+=k0; x1+=k1+3u;
  x0+=x1; x1=rotl_(x1,17); x1^=x0;
  x0+=x1; x1=rotl_(x1,29); x1^=x0;
  x0+=x1; x1=rotl_(x1,16); x1^=x0;
  x0+=x1; x1=rotl_(x1,24); x1^=x0;
  x0+=k1; x1+=k2+4u;
  x0+=x1; x1=rotl_(x1,13); x1^=x0;
  x0+=x1; x1=rotl_(x1,15); x1^=x0;
  x0+=x1; x1=rotl_(x1,26); x1^=x0;
  x0+=x1; x1=rotl_(x1, 6); x1^=x0;
  x0+=k2; x1+=k0+5u;
  o0 = x0; o1 = x1;
}
__device__ __forceinline__ unsigned dropout_bit(unsigned j) {   // 1 = keep
  unsigned o0, o1;
  threefry2x32_(0u, j, o0, o1);
  unsigned bits = o0 ^ o1;
  float u = __uint_as_float((bits >> 9) | 0x3f800000u) - 1.0f;
  return (u < 0.8f) ? 1u : 0u;
}

// ===== stage 1: degrees (global atomics) + coarse hist + weights + mask =====
__global__ __launch_bounds__(256) void k_chist(const int* __restrict__ ei, int E,
                                               int nbk, int N, int wblk,
                                               unsigned* __restrict__ bCntD,
                                               unsigned* __restrict__ srcCnt,
                                               unsigned* __restrict__ dstCnt,
                                               const float* __restrict__ W1,
                                               const float* __restrict__ W2,
                                               unsigned* __restrict__ W1t32,
                                               unsigned* __restrict__ W2t32,
                                               unsigned* __restrict__ bmask) {
  const int t = threadIdx.x;
  if ((int)blockIdx.x >= 256 + wblk) {
    int i = ((int)blockIdx.x - 256 - wblk) * 256 + t;
    if (i < 4 * N) {
      unsigned w = 0;
      #pragma unroll 4
      for (int tbit = 0; tbit < 32; tbit++)
        w |= dropout_bit(32u * (unsigned)i + (unsigned)tbit) << tbit;
      bmask[i] = w;
    }
    return;
  }
  if (blockIdx.x >= 256) {
    int i = (blockIdx.x - 256) * 256 + t;
    if (i < 128 * 128) {
      int n = i >> 7, k = (i & 127) << 1;
      W1t32[i] = pack2bf(W1[(size_t)k * NF1 + n], W1[(size_t)(k + 1) * NF1 + n]);
    } else if (i < 128 * 128 + 48 * 64) {
      int j = i - 128 * 128;
      int f = j >> 6, k = (j & 63) << 1;
      float a = (f < NC) ? W2[(size_t)k * NC + f] : 0.f;
      float c = (f < NC) ? W2[(size_t)(k + 1) * NC + f] : 0.f;
      W2t32[j] = pack2bf(a, c);
    }
    return;
  }
  __shared__ unsigned hd[128];
  for (int i = t; i < 128; i += 256) hd[i] = 0;
  __syncthreads();
  for (int e = blockIdx.x * 256 + t; e < E; e += 256 * 256) {
    int s = ei[e], d = ei[E + e];
    atomicAdd(&srcCnt[s], 1u);
    atomicAdd(&dstCnt[d], 1u);
    atomicAdd(&hd[d >> 10], 1u);
  }
  __syncthreads();
  for (int i = t; i < nbk; i += 256) {
    if (hd[i]) atomicAdd(&bCntD[i], hd[i]);
  }
}

// ===== stage 2: off / norm_dst from bCntD prefix + dstCnt block scan =====
__global__ __launch_bounds__(256) void k_scan(const unsigned* __restrict__ bCntD,
                                              const unsigned* __restrict__ dstCnt,
                                              unsigned* __restrict__ off,
                                              float* __restrict__ norm_dst,
                                              int N, int E, int nbk) {
  __shared__ unsigned sc[128];
  __shared__ unsigned part[256];
  __shared__ unsigned cpreS;
  const int t = threadIdx.x;
  const int b = blockIdx.x;
  unsigned orig = 0;
  if (t < 128) {
    orig = (t < nbk) ? bCntD[t] : 0u;
    sc[t] = orig;
  }
  __syncthreads();
  #pragma unroll
  for (int o = 1; o < 128; o <<= 1) {
    unsigned u = (t < 128 && t >= o) ? sc[t - o] : 0u;
    __syncthreads();
    if (t < 128) sc[t] += u;
    __syncthreads();
  }
  if (t == 0) cpreS = sc[b] - bCntD[b];   // exclusive coarse prefix
  __syncthreads();
  const unsigned cpre = cpreS;
  const int base = b << 10;
  const int n0 = base + 4 * t;
  unsigned c0 = (n0 + 0 < N) ? dstCnt[n0 + 0] : 0u;
  unsigned c1 = (n0 + 1 < N) ? dstCnt[n0 + 1] : 0u;
  unsigned c2 = (n0 + 2 < N) ? dstCnt[n0 + 2] : 0u;
  unsigned c3 = (n0 + 3 < N) ? dstCnt[n0 + 3] : 0u;
  unsigned tsum = c0 + c1 + c2 + c3;
  part[t] = tsum;
  __syncthreads();
  #pragma unroll
  for (int o = 1; o < 256; o <<= 1) {
    unsigned u = (t >= o) ? part[t - o] : 0u;
    __syncthreads();
    part[t] += u;
    __syncthreads();
  }
  unsigned e0 = part[t] - tsum;
  unsigned p0 = e0, p1 = e0 + c0, p2 = p1 + c1, p3 = p2 + c2;
  if (n0 + 0 < N) { off[n0+0] = cpre + p0; norm_dst[n0+0] = 1.0f / sqrtf((float)(c0 < 1u ? 1u : c0)); }
  if (n0 + 1 < N) { off[n0+1] = cpre + p1; norm_dst[n0+1] = 1.0f / sqrtf((float)(c1 < 1u ? 1u : c1)); }
  if (n0 + 2 < N) { off[n0+2] = cpre + p2; norm_dst[n0+2] = 1.0f / sqrtf((float)(c2 < 1u ? 1u : c2)); }
  if (n0 + 3 < N) { off[n0+3] = cpre + p3; norm_dst[n0+3] = 1.0f / sqrtf((float)(c3 < 1u ? 1u : c3)); }
  if (b == nbk - 1 && t == 0) off[N] = (unsigned)E;
}

// ===== stage 3: CSR scatter via global atomics (pd deleted) =====
__global__ __launch_bounds__(256) void k_scatter(const int* __restrict__ ei, int E,
                                                 const unsigned* __restrict__ off,
                                                 unsigned* __restrict__ cur0,
                                                 int* __restrict__ csr) {
  for (int e = blockIdx.x * 256 + threadIdx.x; e < E; e += gridDim.x * 256) {
    int s = ei[e], d = ei[E + e];
    unsigned pos = off[d] + atomicAdd(&cur0[d], 1u);
    csr[pos] = s;
  }
}

// ===== GEMM1 (r12 standalone + srcCnt rsqrt) =====
__global__ __launch_bounds__(256) void k_gemm1(const float* __restrict__ x,
                                               const unsigned* __restrict__ W1t32,
                                               const unsigned* __restrict__ srcCnt,
                                               unsigned short* __restrict__ h1, int N) {
  __shared__ unsigned As[128][20];
  __shared__ unsigned Bs[128][20];
  const int m0 = blockIdx.x * 128;
  const int t = threadIdx.x;
  const int lane = t & 63, wid = t >> 6;
  const int fr = lane & 15, ko = (lane >> 4) * 8;

  f32x4 acc[2][8];
  #pragma unroll
  for (int r = 0; r < 2; r++)
    #pragma unroll
    for (int c = 0; c < 8; c++) acc[r][c] = (f32x4){0.f, 0.f, 0.f, 0.f};

  const int sr = t >> 1;
  const int shw = (t & 1) * 8;

  for (int k0 = 0; k0 < NF0; k0 += 32) {
    {
      unsigned w[8];
      int gm = m0 + sr;
      if (gm < N) {
        const float* p = x + (size_t)gm * NF0 + k0 + shw * 2;
        #pragma unroll
        for (int q = 0; q < 4; q++) {
          float4 v = *(const float4*)(p + q * 4);
          w[2*q]   = pack2bf(v.x, v.y);
          w[2*q+1] = pack2bf(v.z, v.w);
        }
      } else {
        #pragma unroll
        for (int q = 0; q < 8; q++) w[q] = 0u;
      }
      *(uint4*)&As[sr][shw]     = make_uint4(w[0], w[1], w[2], w[3]);
      *(uint4*)&As[sr][shw + 4] = make_uint4(w[4], w[5], w[6], w[7]);
    }
    {
      const unsigned* pb = W1t32 + (size_t)sr * (NF0 / 2) + (k0 >> 1) + shw;
      *(uint4*)&Bs[sr][shw]     = *(const uint4*)pb;
      *(uint4*)&Bs[sr][shw + 4] = *(const uint4*)(pb + 4);
    }
    __syncthreads();
    const unsigned short* As16 = (const unsigned short*)&As[0][0];
    const unsigned short* Bs16 = (const unsigned short*)&Bs[0][0];
    #pragma unroll
    for (int r = 0; r < 2; r++) {
      bfrag a = *(const bfrag*)(As16 + (size_t)(wid * 32 + r * 16 + fr) * 40 + ko);
      #pragma unroll
      for (int c = 0; c < 8; c++) {
        bfrag b = *(const bfrag*)(Bs16 + (size_t)(c * 16 + fr) * 40 + ko);
        acc[r][c] = __builtin_amdgcn_mfma_f32_16x16x32_bf16(a, b, acc[r][c], 0, 0, 0);
      }
    }
    __syncthreads();
  }

  #pragma unroll
  for (int r = 0; r < 2; r++) {
    int rbase = m0 + wid * 32 + r * 16 + (lane >> 4) * 4;
    float ns[4];
    #pragma unroll
    for (int g = 0; g < 4; g++) {
      int row = rbase + g;
      if (row < N) {
        unsigned c = srcCnt[row];
        ns[g] = 1.0f / sqrtf((float)(c < 1u ? 1u : c));
      } else ns[g] = 0.f;
    }
    #pragma unroll
    for (int c = 0; c < 8; c++) {
      int col = c * 16 + fr;
      #pragma unroll
      for (int g = 0; g < 4; g++) {
        int row = rbase + g;
        if (row < N) h1[(size_t)row * NF1 + col] = f2bf(acc[r][c][g] * ns[g]);
      }
    }
  }
}

// ===== fused gather1 + epilogue + GEMM2 (r14 verbatim; measured 90.2us) =====
__global__ __launch_bounds__(256) void k_gather1(const unsigned* __restrict__ off,
                                                 const int* __restrict__ csr,
                                                 const unsigned short* __restrict__ h1,
                                                 const float* __restrict__ norm_dst,
                                                 const unsigned* __restrict__ srcCnt,
                                                 const float* __restrict__ b1,
                                                 const unsigned* __restrict__ bmask,
                                                 const unsigned* __restrict__ W2t32,
                                                 unsigned short* __restrict__ g64,
                                                 int N) {
  const int t = threadIdx.x;
  const int lane = t & 63, wid = t >> 6;
  const int eg = lane >> 4;
  const int q  = lane & 15;
  const float4 bA = *(const float4*)(b1 + q * 8);
  const float4 bB = *(const float4*)(b1 + q * 8 + 4);

  const int wbase = (blockIdx.x * 4 + wid) * 16;
  if (wbase >= N) return;

  uint4 af[4];
  #pragma unroll
  for (int kk = 0; kk < 4; kk++) af[kk] = make_uint4(0u, 0u, 0u, 0u);

  #pragma unroll 1
  for (int i = 0; i < 16; i++) {
    const int node = wbase + i;
    if (node >= N) break;
    unsigned j = off[node], e1 = off[node + 1];
    float ax0=0.f, ax1=0.f, ax2=0.f, ax3=0.f;
    float ay0=0.f, ay1=0.f, ay2=0.f, ay3=0.f;
    for (; j + 8 <= e1; j += 8) {
      int sA = csr[j + eg];
      int sB = csr[j + 4 + eg];
      uint4 vA = *(const uint4*)(h1 + (size_t)sA * NF1 + q * 8);
      uint4 vB = *(const uint4*)(h1 + (size_t)sB * NF1 + q * 8);
      ax0 += bflo(vA.x) + bflo(vB.x); ay0 += bfhi(vA.x) + bfhi(vB.x);
      ax1 += bflo(vA.y) + bflo(vB.y); ay1 += bfhi(vA.y) + bfhi(vB.y);
      ax2 += bflo(vA.z) + bflo(vB.z); ay2 += bfhi(vA.z) + bfhi(vB.z);
      ax3 += bflo(vA.w) + bflo(vB.w); ay3 += bfhi(vA.w) + bfhi(vB.w);
    }
    if (j + 4 <= e1) {
      int s = csr[j + eg];
      uint4 v = *(const uint4*)(h1 + (size_t)s * NF1 + q * 8);
      ax0 += bflo(v.x); ay0 += bfhi(v.x);
      ax1 += bflo(v.y); ay1 += bfhi(v.y);
      ax2 += bflo(v.z); ay2 += bfhi(v.z);
      ax3 += bflo(v.w); ay3 += bfhi(v.w);
      j += 4;
    }
    if (j < e1) {
      unsigned rem = e1 - j;
      if ((unsigned)eg < rem) {
        int s = csr[j + eg];
        uint4 v = *(const uint4*)(h1 + (size_t)s * NF1 + q * 8);
        ax0 += bflo(v.x); ay0 += bfhi(v.x);
        ax1 += bflo(v.y); ay1 += bfhi(v.y);
        ax2 += bflo(v.z); ay2 += bfhi(v.z);
        ax3 += bflo(v.w); ay3 += bfhi(v.w);
      }
    }
    ax0 += __shfl_xor(ax0, 16); ax0 += __shfl_xor(ax0, 32);
    ay0 += __shfl_xor(ay0, 16); ay0 += __shfl_xor(ay0, 32);
    ax1 += __shfl_xor(ax1, 16); ax1 += __shfl_xor(ax1, 32);
    ay1 += __shfl_xor(ay1, 16); ay1 += __shfl_xor(ay1, 32);
    ax2 += __shfl_xor(ax2, 16); ax2 += __shfl_xor(ax2, 32);
    ay2 += __shfl_xor(ay2, 16); ay2 += __shfl_xor(ay2, 32);
    ax3 += __shfl_xor(ax3, 16); ax3 += __shfl_xor(ax3, 32);
    ay3 += __shfl_xor(ay3, 16); ay3 += __shfl_xor(ay3, 32);
    float nd = norm_dst[node];
    unsigned sc = srcCnt[node];
    float ns = 1.0f / sqrtf((float)(sc < 1u ? 1u : sc));
    unsigned mw = bmask[node * 4 + (q >> 2)];
    unsigned mb = (mw >> ((q & 3) * 8)) & 0xffu;
    float v0 = fmaxf(ax0 * nd + bA.x, 0.f);
    float v1 = fmaxf(ay0 * nd + bA.y, 0.f);
    float v2 = fmaxf(ax1 * nd + bA.z, 0.f);
    float v3 = fmaxf(ay1 * nd + bA.w, 0.f);
    float v4 = fmaxf(ax2 * nd + bB.x, 0.f);
    float v5 = fmaxf(ay2 * nd + bB.y, 0.f);
    float v6 = fmaxf(ax3 * nd + bB.z, 0.f);
    float v7 = fmaxf(ay3 * nd + bB.w, 0.f);
    v0 *= ((mb >> 0) & 1 ? 1.25f : 0.f) * ns;
    v1 *= ((mb >> 1) & 1 ? 1.25f : 0.f) * ns;
    v2 *= ((mb >> 2) & 1 ? 1.25f : 0.f) * ns;
    v3 *= ((mb >> 3) & 1 ? 1.25f : 0.f) * ns;
    v4 *= ((mb >> 4) & 1 ? 1.25f : 0.f) * ns;
    v5 *= ((mb >> 5) & 1 ? 1.25f : 0.f) * ns;
    v6 *= ((mb >> 6) & 1 ? 1.25f : 0.f) * ns;
    v7 *= ((mb >> 7) & 1 ? 1.25f : 0.f) * ns;
    uint4 o;
    o.x = pack2bf(v0, v1);
    o.y = pack2bf(v2, v3);
    o.z = pack2bf(v4, v5);
    o.w = pack2bf(v6, v7);
    #pragma unroll
    for (int kk = 0; kk < 4; kk++) {
      int srcl = 4 * kk + eg;
      unsigned t0 = __shfl(o.x, srcl);
      unsigned t1 = __shfl(o.y, srcl);
      unsigned t2 = __shfl(o.z, srcl);
      unsigned t3 = __shfl(o.w, srcl);
      if (q == i) af[kk] = make_uint4(t0, t1, t2, t3);
    }
  }

  #pragma unroll
  for (int c = 0; c < 3; c++) {
    f32x4 acc = (f32x4){0.f, 0.f, 0.f, 0.f};
    const unsigned* bp = W2t32 + (size_t)(c * 16 + q) * 64 + eg * 4;
    #pragma unroll
    for (int kk = 0; kk < 4; kk++) {
      uint4 w = *(const uint4*)(bp + kk * 16);
      acc = __builtin_amdgcn_mfma_f32_16x16x32_bf16(*(bfrag*)&af[kk], *(bfrag*)&w,
                                                    acc, 0, 0, 0);
    }
    int col = c * 16 + q;
    #pragma unroll
    for (int r = 0; r < 4; r++) {
      int nr = wbase + eg * 4 + r;
      if (nr < N) g64[(size_t)nr * 64 + col] = f2bf(acc[r]);
    }
  }
  #pragma unroll
  for (int r = 0; r < 4; r++) {
    int nr = wbase + eg * 4 + r;
    if (nr < N) g64[(size_t)nr * 64 + 48 + q] = 0;
  }
}

// ===== gather2 + bias + log_softmax (r12 verbatim) =====
__global__ __launch_bounds__(256) void k_gather2(const unsigned* __restrict__ off,
                                                 const int* __restrict__ csr,
                                                 const unsigned* __restrict__ g64,
                                                 const float* __restrict__ norm_dst,
                                                 const float* __restrict__ b2,
                                                 float* __restrict__ out, int N) {
  int node = (blockIdx.x * 256 + threadIdx.x) >> 6;
  int lane = threadIdx.x & 63;
  if (node >= N) return;
  const int h = lane >> 5, q = lane & 31;
  unsigned j = off[node], e1 = off[node + 1];
  float a0 = 0.f, a1 = 0.f;
  for (; j + 8 <= e1; j += 8) {
    int s0 = csr[j + h],     s1 = csr[j + 2 + h];
    int s2 = csr[j + 4 + h], s3 = csr[j + 6 + h];
    unsigned v0 = g64[(size_t)s0 * 32 + q];
    unsigned v1 = g64[(size_t)s1 * 32 + q];
    unsigned v2 = g64[(size_t)s2 * 32 + q];
    unsigned v3 = g64[(size_t)s3 * 32 + q];
    a0 += (bflo(v0) + bflo(v1)) + (bflo(v2) + bflo(v3));
    a1 += (bfhi(v0) + bfhi(v1)) + (bfhi(v2) + bfhi(v3));
  }
  if (j + 4 <= e1) {
    int sA = csr[j + h], sB = csr[j + 2 + h];
    unsigned vA = g64[(size_t)sA * 32 + q];
    unsigned vB = g64[(size_t)sB * 32 + q];
    a0 += bflo(vA) + bflo(vB);
    a1 += bfhi(vA) + bfhi(vB);
    j += 4;
  }
  if (j + 2 <= e1) {
    int s = csr[j + h];
    unsigned v = g64[(size_t)s * 32 + q];
    a0 += bflo(v); a1 += bfhi(v);
    j += 2;
  }
  if (j < e1 && h == 0) {
    int s = csr[j];
    unsigned v = g64[(size_t)s * 32 + q];
    a0 += bflo(v); a1 += bfhi(v);
  }
  a0 += __shfl_xor(a0, 32);
  a1 += __shfl_xor(a1, 32);
  float nd = norm_dst[node];
  int f0 = 2 * q, f1 = 2 * q + 1;
  float v0 = (f0 < NC) ? a0 * nd + b2[f0] : -INFINITY;
  float v1 = (f1 < NC) ? a1 * nd + b2[f1] : -INFINITY;
  float m = fmaxf(v0, v1);
  #pragma unroll
  for (int o = 16; o; o >>= 1) m = fmaxf(m, __shfl_xor(m, o));
  float ex = ((f0 < NC) ? expf(v0 - m) : 0.f) + ((f1 < NC) ? expf(v1 - m) : 0.f);
  #pragma unroll
  for (int o = 16; o; o >>= 1) ex += __shfl_xor(ex, o);
  float ls = logf(ex);
  if (h == 0) {
    if (f0 < NC) out[(size_t)node * NC + f0] = v0 - m - ls;
    if (f1 < NC) out[(size_t)node * NC + f1] = v1 - m - ls;
  }
}

extern "C" void kernel_launch(void* const* d_in, const int* in_sizes, int n_in,
                              void* d_out, int out_size, void* d_ws, size_t ws_size,
                              hipStream_t stream) {
  const float* x  = (const float*)d_in[0];
  const int*   ei = (const int*)d_in[1];
  const float* W1 = (const float*)d_in[2];
  const float* b1 = (const float*)d_in[3];
  const float* W2 = (const float*)d_in[4];
  const float* b2 = (const float*)d_in[5];
  float* out = (float*)d_out;

  const int N = in_sizes[0] / NF0;   // 100000
  const int E = in_sizes[1] / 2;     // 1600000
  const int nbk = (N + CB - 1) / CB; // 98
  const int Npad = (N + 63) & ~63;

  unsigned* ws = (unsigned*)d_ws;
  size_t o = 0;
  auto alloc = [&](size_t elems) { size_t p = o; o += (elems + 3) & ~(size_t)3; return p; };
  float*    norm_dst = (float*)(ws + alloc(N));
  unsigned* off      = ws + alloc(N + 1);
  unsigned* bCntD    = ws + alloc(128);   // bCntD,srcCnt,dstCnt,cur0 contiguous: one memset
  unsigned* srcCnt   = ws + alloc(N);
  unsigned* dstCnt   = ws + alloc(N);
  unsigned* cur0     = ws + alloc(N);
  unsigned* bmask    = ws + alloc((size_t)4 * N);            // 1.6 MB dropout bitmask
  int*      csr      = (int*)(ws + alloc(E));                // 6.4 MB
  unsigned* W1t32    = ws + alloc(128 * 128);
  unsigned* W2t32    = ws + alloc(48 * 64);
  unsigned short* h1 = (unsigned short*)(ws + alloc((size_t)N * NF1 / 2));
  unsigned* g64u     = ws + alloc((size_t)Npad * 32);        // 12.8 MB g64 rows
  unsigned short* g64 = (unsigned short*)g64u;

  hipMemsetAsync(bCntD, 0, (size_t)(128 + 3 * N) * sizeof(unsigned), stream);

  int wblk = (128 * 128 + 48 * 64 + 255) / 256;  // 76
  int mblk = (4 * N + 255) / 256;                // 1563
  k_chist<<<256 + wblk + mblk, 256, 0, stream>>>(ei, E, nbk, N, wblk, bCntD,
                                                 srcCnt, dstCnt, W1, W2,
                                                 W1t32, W2t32, bmask);
  k_scan<<<nbk, 256, 0, stream>>>(bCntD, dstCnt, off, norm_dst, N, E, nbk);
  k_scatter<<<1024, 256, 0, stream>>>(ei, E, off, cur0, csr);
  k_gemm1<<<(N + 127) / 128, 256, 0, stream>>>(x, W1t32, srcCnt, h1, N);
  k_gather1<<<(N + 63) / 64, 256, 0, stream>>>(off, csr, h1, norm_dst, srcCnt,
                                               b1, bmask, W2t32, g64, N);
  k_gather2<<<((size_t)N * 64 + 255) / 256, 256, 0, stream>>>(
      off, csr, (const unsigned*)g64u, norm_dst, b2, out, N);
}

// Round 9
// 434.090 us; speedup vs baseline: 1.3506x; 1.3506x over previous
//
#include <hip/hip_runtime.h>
#include <math.h>

// GCN 2-layer forward, MI355X. Round 16: full revert to r12 (436.2us measured
// best; r13/r14/r15 all regressed: persistent-loop VGPR cliff, hetero-role
// fusion allocation cliff, per-edge global-atomic storm). Single change vs
// r12: gather1/gather2 run as 128-thread (2-wave) blocks -> 2x block count,
// finer per-CU refill granularity, smaller drain tail. Bodies untouched.

#define NF0 256
#define NF1 128
#define NC  47
#define CB  1024   // fine bucket width (nodes per coarse bucket); nbk<=128

typedef __attribute__((ext_vector_type(8))) short bfrag;   // 8 bf16 (4 VGPRs)
typedef __attribute__((ext_vector_type(4))) float f32x4;

__device__ __forceinline__ unsigned short f2bf(float f) {   // RNE
  unsigned u = __float_as_uint(f);
  return (unsigned short)((u + 0x7fffu + ((u >> 16) & 1u)) >> 16);
}
__device__ __forceinline__ unsigned pack2bf(float a, float b) {
  return (unsigned)f2bf(a) | ((unsigned)f2bf(b) << 16);
}
__device__ __forceinline__ float bflo(unsigned v) { return __uint_as_float(v << 16); }
__device__ __forceinline__ float bfhi(unsigned v) { return __uint_as_float(v & 0xffff0000u); }

// ---------------- threefry2x32 (JAX partitionable path; verified r1/r2) ------------
__device__ __forceinline__ unsigned rotl_(unsigned x, int n) {
  return (x << n) | (x >> (32 - n));
}
__device__ __forceinline__ void threefry2x32_(unsigned x0, unsigned x1,
                                              unsigned& o0, unsigned& o1) {
  const unsigned k0 = 0u, k1 = 42u;
  const unsigned k2 = k0 ^ k1 ^ 0x1BD11BDAu;
  x0 += k0; x1 += k1;
  x0+=x1; x1=rotl_(x1,13); x1^=x0;
  x0+=x1; x1=rotl_(x1,15); x1^=x0;
  x0+=x1; x1=rotl_(x1,26); x1^=x0;
  x0+=x1; x1=rotl_(x1, 6); x1^=x0;
  x0+=k1; x1+=k2+1u;
  x0+=x1; x1=rotl_(x1,17); x1^=x0;
  x0+=x1; x1=rotl_(x1,29); x1^=x0;
  x0+=x1; x1=rotl_(x1,16); x1^=x0;
  x0+=x1; x1=rotl_(x1,24); x1^=x0;
  x0+=k2; x1+=k0+2u;
  x0+=x1; x1=rotl_(x1,13); x1^=x0;
  x0+=x1; x1=rotl_(x1,15); x1^=x0;
  x0+=x1; x1=rotl_(x1,26); x1^=x0;
  x0+=x1; x1=rotl_(x1, 6); x1^=x0;
  x0+=k0; x1+=k1+3u;
  x0+=x1; x1=rotl_(x1,17); x1^=x0;
  x0+=x1; x1=rotl_(x1,29); x1^=x0;
  x0+=x1; x1=rotl_(x1,16); x1^=x0;
  x0+=x1; x1=rotl_(x1,24); x1^=x0;
  x0+=k1; x1+=k2+4u;
  x0+=x1; x1=rotl_(x1,13); x1^=x0;
  x0+=x1; x1=rotl_(x1,15); x1^=x0;
  x0+=x1; x1=rotl_(x1,26); x1^=x0;
  x0+=x1; x1=rotl_(x1, 6); x1^=x0;
  x0+=k2; x1+=k0+5u;
  o0 = x0; o1 = x1;
}
__device__ __forceinline__ unsigned dropout_bit(unsigned j) {   // 1 = keep
  unsigned o0, o1;
  threefry2x32_(0u, j, o0, o1);
  unsigned bits = o0 ^ o1;
  float u = __uint_as_float((bits >> 9) | 0x3f800000u) - 1.0f;
  return (u < 0.8f) ? 1u : 0u;
}

// ================= preprocessing =================

// P1: coarse histogram (blocks 0..255) + weight convert (blocks >=256).
__global__ __launch_bounds__(256) void k_chist(const int* __restrict__ ei, int E,
                                               int nbk,
                                               unsigned* __restrict__ bCntD,
                                               unsigned* __restrict__ bCntS,
                                               const float* __restrict__ W1,
                                               const float* __restrict__ W2,
                                               unsigned* __restrict__ W1t32,
                                               unsigned* __restrict__ W2t32) {
  if (blockIdx.x >= 256) {
    int i = (blockIdx.x - 256) * 256 + threadIdx.x;
    if (i < 128 * 128) {
      int n = i >> 7, k = (i & 127) << 1;
      W1t32[i] = pack2bf(W1[(size_t)k * NF1 + n], W1[(size_t)(k + 1) * NF1 + n]);
    } else if (i < 128 * 128 + 48 * 64) {
      int j = i - 128 * 128;
      int f = j >> 6, k = (j & 63) << 1;
      float a = (f < NC) ? W2[(size_t)k * NC + f] : 0.f;
      float c = (f < NC) ? W2[(size_t)(k + 1) * NC + f] : 0.f;
      W2t32[j] = pack2bf(a, c);
    }
    return;
  }
  __shared__ unsigned hd[128], hs[128];
  for (int i = threadIdx.x; i < 128; i += 256) { hd[i] = 0; hs[i] = 0; }
  __syncthreads();
  for (int e = blockIdx.x * 256 + threadIdx.x; e < E; e += 256 * 256) {
    int s = ei[e], d = ei[E + e];
    atomicAdd(&hs[s >> 10], 1u);
    atomicAdd(&hd[d >> 10], 1u);
  }
  __syncthreads();
  for (int i = threadIdx.x; i < nbk; i += 256) {
    if (hd[i]) atomicAdd(&bCntD[i], hd[i]);
    if (hs[i]) atomicAdd(&bCntS[i], hs[i]);
  }
}

// P2: coarse scatter with per-block LDS scan of coarse counts + chunk reservation.
__global__ __launch_bounds__(256) void k_cscatter(const int* __restrict__ ei, int E,
                                                  const unsigned* __restrict__ bCntD,
                                                  const unsigned* __restrict__ bCntS,
                                                  unsigned* __restrict__ curD,
                                                  unsigned* __restrict__ curS,
                                                  unsigned* __restrict__ pd,
                                                  unsigned short* __restrict__ ps,
                                                  int nbk) {
  __shared__ unsigned hd[128], hs[128];
  __shared__ unsigned baseD[128], baseS[128];
  __shared__ unsigned sc[256];
  const int t = threadIdx.x;
  int per = (E + gridDim.x - 1) / gridDim.x;
  int e0 = blockIdx.x * per;
  int e1 = min(e0 + per, E);
  unsigned orig = (t < 128) ? ((t < nbk) ? bCntD[t] : 0u)
                            : (((t - 128) < nbk) ? bCntS[t - 128] : 0u);
  sc[t] = orig;
  if (t < 128) { hd[t] = 0; hs[t] = 0; }
  __syncthreads();
  for (int e = e0 + t; e < e1; e += 256) {
    int s = ei[e], d = ei[E + e];
    atomicAdd(&hs[s >> 10], 1u);
    atomicAdd(&hd[d >> 10], 1u);
  }
  __syncthreads();
  #pragma unroll
  for (int o = 1; o < 128; o <<= 1) {
    unsigned u = ((t & 127) >= o) ? sc[t - o] : 0u;
    __syncthreads();
    sc[t] += u;
    __syncthreads();
  }
  if (t < 128) {
    unsigned excl = sc[t] - orig;
    unsigned h = hd[t];
    baseD[t] = excl + (h ? atomicAdd(&curD[t], h) : 0u);
    hd[t] = 0;
  } else {
    int i = t - 128;
    unsigned excl = sc[t] - orig;
    unsigned h = hs[i];
    baseS[i] = excl + (h ? atomicAdd(&curS[i], h) : 0u);
    hs[i] = 0;
  }
  __syncthreads();
  for (int e = e0 + t; e < e1; e += 256) {
    int s = ei[e], d = ei[E + e];
    int bd = d >> 10, bs = s >> 10;
    unsigned pD = baseD[bd] + atomicAdd(&hd[bd], 1u);
    unsigned pS = baseS[bs] + atomicAdd(&hs[bs], 1u);
    pd[pD] = ((unsigned)(d & (CB - 1)) << 17) | (unsigned)s;
    ps[pS] = (unsigned short)(s & (CB - 1));
  }
}

// P3: fused fine pass, grid = 2*nbk + mblk. Blocks >= 2*nbk generate the
// dropout bitmask (pure VALU) on the CUs the fine blocks leave idle.
__global__ __launch_bounds__(256) void k_fine(const unsigned* __restrict__ bCntD,
                                              const unsigned* __restrict__ bCntS,
                                              const unsigned* __restrict__ pd,
                                              const unsigned short* __restrict__ ps,
                                              unsigned* __restrict__ off,
                                              float* __restrict__ norm_dst,
                                              float* __restrict__ norm_src,
                                              int* __restrict__ csr,
                                              int N, int E, int nbk,
                                              unsigned* __restrict__ bmask) {
  const int t = threadIdx.x;
  if ((int)blockIdx.x >= 2 * nbk) {
    int i = ((int)blockIdx.x - 2 * nbk) * 256 + t;
    if (i < 4 * N) {
      unsigned w = 0;
      #pragma unroll 4
      for (int tbit = 0; tbit < 32; tbit++)
        w |= dropout_bit(32u * (unsigned)i + (unsigned)tbit) << tbit;
      bmask[i] = w;
    }
    return;
  }
  __shared__ unsigned cnt[CB];
  __shared__ unsigned part[256];
  __shared__ unsigned sc[256];
  const bool isD = (int)blockIdx.x < nbk;
  const int b = isD ? (int)blockIdx.x : ((int)blockIdx.x - nbk);
  unsigned orig = (t < 128) ? ((t < nbk) ? bCntD[t] : 0u)
                            : (((t - 128) < nbk) ? bCntS[t - 128] : 0u);
  sc[t] = orig;
  __syncthreads();
  #pragma unroll
  for (int o = 1; o < 128; o <<= 1) {
    unsigned u = ((t & 127) >= o) ? sc[t - o] : 0u;
    __syncthreads();
    sc[t] += u;
    __syncthreads();
  }
  const int idx = isD ? b : (128 + b);
  const unsigned hi = sc[idx];
  const unsigned lo = hi - (isD ? bCntD[b] : bCntS[b]);
  const int base = b << 10;
  for (int i = t; i < CB; i += 256) cnt[i] = 0;
  __syncthreads();
  if (isD) {
    for (unsigned j = lo + t; j < hi; j += 256) atomicAdd(&cnt[pd[j] >> 17], 1u);
    __syncthreads();
    unsigned c0 = cnt[4*t], c1 = cnt[4*t+1], c2 = cnt[4*t+2], c3 = cnt[4*t+3];
    unsigned tsum = c0 + c1 + c2 + c3;
    part[t] = tsum;
    __syncthreads();
    #pragma unroll
    for (int o = 1; o < 256; o <<= 1) {
      unsigned u = (t >= o) ? part[t - o] : 0u;
      __syncthreads();
      part[t] += u;
      __syncthreads();
    }
    unsigned e0 = part[t] - tsum;
    unsigned p0 = e0, p1 = e0 + c0, p2 = p1 + c1, p3 = p2 + c2;
    int n0 = base + 4 * t;
    if (n0 + 0 < N) { off[n0+0] = lo + p0; norm_dst[n0+0] = 1.0f / sqrtf((float)(c0 < 1u ? 1u : c0)); }
    if (n0 + 1 < N) { off[n0+1] = lo + p1; norm_dst[n0+1] = 1.0f / sqrtf((float)(c1 < 1u ? 1u : c1)); }
    if (n0 + 2 < N) { off[n0+2] = lo + p2; norm_dst[n0+2] = 1.0f / sqrtf((float)(c2 < 1u ? 1u : c2)); }
    if (n0 + 3 < N) { off[n0+3] = lo + p3; norm_dst[n0+3] = 1.0f / sqrtf((float)(c3 < 1u ? 1u : c3)); }
    if (b == nbk - 1 && t == 0) off[N] = (unsigned)E;
    __syncthreads();
    cnt[4*t] = p0; cnt[4*t+1] = p1; cnt[4*t+2] = p2; cnt[4*t+3] = p3;   // cursors
    __syncthreads();
    for (unsigned j = lo + t; j < hi; j += 256) {
      unsigned v = pd[j];
      unsigned pos = atomicAdd(&cnt[v >> 17], 1u);
      csr[lo + pos] = (int)(v & 0x1FFFFu);
    }
  } else {
    for (unsigned j = lo + t; j < hi; j += 256) atomicAdd(&cnt[ps[j]], 1u);
    __syncthreads();
    for (int i = t; i < CB; i += 256) {
      int n = base + i;
      if (n < N) {
        unsigned c = cnt[i];
        norm_src[n] = 1.0f / sqrtf((float)(c < 1u ? 1u : c));
      }
    }
  }
}

// ---------------- GEMM1 (MFMA bf16): h1[m,n] = ns[m] * sum_k x[m,k] W1[k,n] --------
__global__ __launch_bounds__(256) void k_gemm1(const float* __restrict__ x,
                                               const unsigned* __restrict__ W1t32,
                                               const float* __restrict__ norm_src,
                                               unsigned short* __restrict__ h1, int N) {
  __shared__ unsigned As[128][20];   // 16 used + 4 pad
  __shared__ unsigned Bs[128][20];
  const int m0 = blockIdx.x * 128;
  const int t = threadIdx.x;
  const int lane = t & 63, wid = t >> 6;
  const int fr = lane & 15, ko = (lane >> 4) * 8;

  f32x4 acc[2][8];
  #pragma unroll
  for (int r = 0; r < 2; r++)
    #pragma unroll
    for (int c = 0; c < 8; c++) acc[r][c] = (f32x4){0.f, 0.f, 0.f, 0.f};

  const int sr = t >> 1;
  const int shw = (t & 1) * 8;

  for (int k0 = 0; k0 < NF0; k0 += 32) {
    {
      unsigned w[8];
      int gm = m0 + sr;
      if (gm < N) {
        const float* p = x + (size_t)gm * NF0 + k0 + shw * 2;
        #pragma unroll
        for (int q = 0; q < 4; q++) {
          float4 v = *(const float4*)(p + q * 4);
          w[2*q]   = pack2bf(v.x, v.y);
          w[2*q+1] = pack2bf(v.z, v.w);
        }
      } else {
        #pragma unroll
        for (int q = 0; q < 8; q++) w[q] = 0u;
      }
      *(uint4*)&As[sr][shw]     = make_uint4(w[0], w[1], w[2], w[3]);
      *(uint4*)&As[sr][shw + 4] = make_uint4(w[4], w[5], w[6], w[7]);
    }
    {
      const unsigned* pb = W1t32 + (size_t)sr * (NF0 / 2) + (k0 >> 1) + shw;
      *(uint4*)&Bs[sr][shw]     = *(const uint4*)pb;
      *(uint4*)&Bs[sr][shw + 4] = *(const uint4*)(pb + 4);
    }
    __syncthreads();
    const unsigned short* As16 = (const unsigned short*)&As[0][0];
    const unsigned short* Bs16 = (const unsigned short*)&Bs[0][0];
    #pragma unroll
    for (int r = 0; r < 2; r++) {
      bfrag a = *(const bfrag*)(As16 + (size_t)(wid * 32 + r * 16 + fr) * 40 + ko);
      #pragma unroll
      for (int c = 0; c < 8; c++) {
        bfrag b = *(const bfrag*)(Bs16 + (size_t)(c * 16 + fr) * 40 + ko);
        acc[r][c] = __builtin_amdgcn_mfma_f32_16x16x32_bf16(a, b, acc[r][c], 0, 0, 0);
      }
    }
    __syncthreads();
  }

  #pragma unroll
  for (int r = 0; r < 2; r++) {
    int rbase = m0 + wid * 32 + r * 16 + (lane >> 4) * 4;
    float ns[4];
    #pragma unroll
    for (int g = 0; g < 4; g++) ns[g] = (rbase + g < N) ? norm_src[rbase + g] : 0.f;
    #pragma unroll
    for (int c = 0; c < 8; c++) {
      int col = c * 16 + fr;
      #pragma unroll
      for (int g = 0; g < 4; g++) {
        int row = rbase + g;
        if (row < N) h1[(size_t)row * NF1 + col] = f2bf(acc[r][c][g] * ns[g]);
      }
    }
  }
}

// ------- fused gather1 + epilogue + GEMM2 (wave = 16 nodes, zero LDS) -------
// r12 body verbatim; 128-thread blocks (2 waves) for finer scheduling
// granularity (r12 measured occ 58% @ 4-wave blocks; tail/refill imbalance).
__global__ __launch_bounds__(128) void k_gather1(const unsigned* __restrict__ off,
                                                 const int* __restrict__ csr,
                                                 const unsigned short* __restrict__ h1,
                                                 const float* __restrict__ norm_dst,
                                                 const float* __restrict__ norm_src,
                                                 const float* __restrict__ b1,
                                                 const unsigned* __restrict__ bmask,
                                                 const unsigned* __restrict__ W2t32,
                                                 unsigned short* __restrict__ g64,
                                                 int N) {
  const int t = threadIdx.x;
  const int lane = t & 63, wid = t >> 6;       // wid in {0,1}
  const int eg = lane >> 4;      // edge subgroup 0..3  == A-frag K-group
  const int q  = lane & 15;      // 16B slice of row    == A-frag row id
  const float4 bA = *(const float4*)(b1 + q * 8);
  const float4 bB = *(const float4*)(b1 + q * 8 + 4);

  const int wbase = (blockIdx.x * 2 + wid) * 16;
  if (wbase >= N) return;

  uint4 af[4];
  #pragma unroll
  for (int kk = 0; kk < 4; kk++) af[kk] = make_uint4(0u, 0u, 0u, 0u);

  #pragma unroll 1
  for (int i = 0; i < 16; i++) {
    const int node = wbase + i;
    if (node >= N) break;
    unsigned j = off[node], e1 = off[node + 1];
    float ax0=0.f, ax1=0.f, ax2=0.f, ax3=0.f;
    float ay0=0.f, ay1=0.f, ay2=0.f, ay3=0.f;
    for (; j + 8 <= e1; j += 8) {
      int sA = csr[j + eg];
      int sB = csr[j + 4 + eg];
      uint4 vA = *(const uint4*)(h1 + (size_t)sA * NF1 + q * 8);
      uint4 vB = *(const uint4*)(h1 + (size_t)sB * NF1 + q * 8);
      ax0 += bflo(vA.x) + bflo(vB.x); ay0 += bfhi(vA.x) + bfhi(vB.x);
      ax1 += bflo(vA.y) + bflo(vB.y); ay1 += bfhi(vA.y) + bfhi(vB.y);
      ax2 += bflo(vA.z) + bflo(vB.z); ay2 += bfhi(vA.z) + bfhi(vB.z);
      ax3 += bflo(vA.w) + bflo(vB.w); ay3 += bfhi(vA.w) + bfhi(vB.w);
    }
    if (j + 4 <= e1) {
      int s = csr[j + eg];
      uint4 v = *(const uint4*)(h1 + (size_t)s * NF1 + q * 8);
      ax0 += bflo(v.x); ay0 += bfhi(v.x);
      ax1 += bflo(v.y); ay1 += bfhi(v.y);
      ax2 += bflo(v.z); ay2 += bfhi(v.z);
      ax3 += bflo(v.w); ay3 += bfhi(v.w);
      j += 4;
    }
    if (j < e1) {
      unsigned rem = e1 - j;   // 1..3
      if ((unsigned)eg < rem) {
        int s = csr[j + eg];
        uint4 v = *(const uint4*)(h1 + (size_t)s * NF1 + q * 8);
        ax0 += bflo(v.x); ay0 += bfhi(v.x);
        ax1 += bflo(v.y); ay1 += bfhi(v.y);
        ax2 += bflo(v.z); ay2 += bfhi(v.z);
        ax3 += bflo(v.w); ay3 += bfhi(v.w);
      }
    }
    // combine the 4 edge subgroups (all lanes end with full sums)
    ax0 += __shfl_xor(ax0, 16); ax0 += __shfl_xor(ax0, 32);
    ay0 += __shfl_xor(ay0, 16); ay0 += __shfl_xor(ay0, 32);
    ax1 += __shfl_xor(ax1, 16); ax1 += __shfl_xor(ax1, 32);
    ay1 += __shfl_xor(ay1, 16); ay1 += __shfl_xor(ay1, 32);
    ax2 += __shfl_xor(ax2, 16); ax2 += __shfl_xor(ax2, 32);
    ay2 += __shfl_xor(ay2, 16); ay2 += __shfl_xor(ay2, 32);
    ax3 += __shfl_xor(ax3, 16); ax3 += __shfl_xor(ax3, 32);
    ay3 += __shfl_xor(ay3, 16); ay3 += __shfl_xor(ay3, 32);
    // all-lane epilogue (each 16-lane quadrant computes the identical row)
    float nd = norm_dst[node], ns = norm_src[node];
    unsigned mw = bmask[node * 4 + (q >> 2)];
    unsigned mb = (mw >> ((q & 3) * 8)) & 0xffu;
    float v0 = fmaxf(ax0 * nd + bA.x, 0.f);
    float v1 = fmaxf(ay0 * nd + bA.y, 0.f);
    float v2 = fmaxf(ax1 * nd + bA.z, 0.f);
    float v3 = fmaxf(ay1 * nd + bA.w, 0.f);
    float v4 = fmaxf(ax2 * nd + bB.x, 0.f);
    float v5 = fmaxf(ay2 * nd + bB.y, 0.f);
    float v6 = fmaxf(ax3 * nd + bB.z, 0.f);
    float v7 = fmaxf(ay3 * nd + bB.w, 0.f);
    v0 *= ((mb >> 0) & 1 ? 1.25f : 0.f) * ns;
    v1 *= ((mb >> 1) & 1 ? 1.25f : 0.f) * ns;
    v2 *= ((mb >> 2) & 1 ? 1.25f : 0.f) * ns;
    v3 *= ((mb >> 3) & 1 ? 1.25f : 0.f) * ns;
    v4 *= ((mb >> 4) & 1 ? 1.25f : 0.f) * ns;
    v5 *= ((mb >> 5) & 1 ? 1.25f : 0.f) * ns;
    v6 *= ((mb >> 6) & 1 ? 1.25f : 0.f) * ns;
    v7 *= ((mb >> 7) & 1 ? 1.25f : 0.f) * ns;
    uint4 o;
    o.x = pack2bf(v0, v1);
    o.y = pack2bf(v2, v3);
    o.z = pack2bf(v4, v5);
    o.w = pack2bf(v6, v7);
    // A-fragment select: lane (q,eg) keeps uint4 of lane 4*kk+eg when q==i
    #pragma unroll
    for (int kk = 0; kk < 4; kk++) {
      int srcl = 4 * kk + eg;
      unsigned t0 = __shfl(o.x, srcl);
      unsigned t1 = __shfl(o.y, srcl);
      unsigned t2 = __shfl(o.z, srcl);
      unsigned t3 = __shfl(o.w, srcl);
      if (q == i) af[kk] = make_uint4(t0, t1, t2, t3);
    }
  }

  // ---- per-wave MFMA GEMM2: rows wbase..wbase+15 x 48 cols ----
  #pragma unroll
  for (int c = 0; c < 3; c++) {
    f32x4 acc = (f32x4){0.f, 0.f, 0.f, 0.f};
    const unsigned* bp = W2t32 + (size_t)(c * 16 + q) * 64 + eg * 4;
    #pragma unroll
    for (int kk = 0; kk < 4; kk++) {
      uint4 w = *(const uint4*)(bp + kk * 16);
      acc = __builtin_amdgcn_mfma_f32_16x16x32_bf16(*(bfrag*)&af[kk], *(bfrag*)&w,
                                                    acc, 0, 0, 0);
    }
    int col = c * 16 + q;
    #pragma unroll
    for (int r = 0; r < 4; r++) {
      int nr = wbase + eg * 4 + r;
      if (nr < N) g64[(size_t)nr * 64 + col] = f2bf(acc[r]);
    }
  }
  #pragma unroll
  for (int r = 0; r < 4; r++) {
    int nr = wbase + eg * 4 + r;
    if (nr < N) g64[(size_t)nr * 64 + 48 + q] = 0;
  }
}

// ---------------- gather2 + bias + log_softmax -> out ----------------
// r12 body verbatim; 128-thread blocks.
__global__ __launch_bounds__(128) void k_gather2(const unsigned* __restrict__ off,
                                                 const int* __restrict__ csr,
                                                 const unsigned* __restrict__ g64,
                                                 const float* __restrict__ norm_dst,
                                                 const float* __restrict__ b2,
                                                 float* __restrict__ out, int N) {
  int node = (blockIdx.x * 128 + threadIdx.x) >> 6;
  int lane = threadIdx.x & 63;
  if (node >= N) return;
  const int h = lane >> 5, q = lane & 31;
  unsigned j = off[node], e1 = off[node + 1];
  float a0 = 0.f, a1 = 0.f;
  for (; j + 8 <= e1; j += 8) {
    int s0 = csr[j + h],     s1 = csr[j + 2 + h];
    int s2 = csr[j + 4 + h], s3 = csr[j + 6 + h];
    unsigned v0 = g64[(size_t)s0 * 32 + q];
    unsigned v1 = g64[(size_t)s1 * 32 + q];
    unsigned v2 = g64[(size_t)s2 * 32 + q];
    unsigned v3 = g64[(size_t)s3 * 32 + q];
    a0 += (bflo(v0) + bflo(v1)) + (bflo(v2) + bflo(v3));
    a1 += (bfhi(v0) + bfhi(v1)) + (bfhi(v2) + bfhi(v3));
  }
  if (j + 4 <= e1) {
    int sA = csr[j + h], sB = csr[j + 2 + h];
    unsigned vA = g64[(size_t)sA * 32 + q];
    unsigned vB = g64[(size_t)sB * 32 + q];
    a0 += bflo(vA) + bflo(vB);
    a1 += bfhi(vA) + bfhi(vB);
    j += 4;
  }
  if (j + 2 <= e1) {
    int s = csr[j + h];
    unsigned v = g64[(size_t)s * 32 + q];
    a0 += bflo(v); a1 += bfhi(v);
    j += 2;
  }
  if (j < e1 && h == 0) {
    int s = csr[j];
    unsigned v = g64[(size_t)s * 32 + q];
    a0 += bflo(v); a1 += bfhi(v);
  }
  a0 += __shfl_xor(a0, 32);
  a1 += __shfl_xor(a1, 32);
  // lane q holds sums for feats 2q, 2q+1 (both halves identical now)
  float nd = norm_dst[node];
  int f0 = 2 * q, f1 = 2 * q + 1;
  float v0 = (f0 < NC) ? a0 * nd + b2[f0] : -INFINITY;
  float v1 = (f1 < NC) ? a1 * nd + b2[f1] : -INFINITY;
  float m = fmaxf(v0, v1);
  #pragma unroll
  for (int o = 16; o; o >>= 1) m = fmaxf(m, __shfl_xor(m, o));
  float ex = ((f0 < NC) ? expf(v0 - m) : 0.f) + ((f1 < NC) ? expf(v1 - m) : 0.f);
  #pragma unroll
  for (int o = 16; o; o >>= 1) ex += __shfl_xor(ex, o);
  float ls = logf(ex);
  if (h == 0) {
    if (f0 < NC) out[(size_t)node * NC + f0] = v0 - m - ls;
    if (f1 < NC) out[(size_t)node * NC + f1] = v1 - m - ls;
  }
}

extern "C" void kernel_launch(void* const* d_in, const int* in_sizes, int n_in,
                              void* d_out, int out_size, void* d_ws, size_t ws_size,
                              hipStream_t stream) {
  const float* x  = (const float*)d_in[0];
  const int*   ei = (const int*)d_in[1];
  const float* W1 = (const float*)d_in[2];
  const float* b1 = (const float*)d_in[3];
  const float* W2 = (const float*)d_in[4];
  const float* b2 = (const float*)d_in[5];
  float* out = (float*)d_out;

  const int N = in_sizes[0] / NF0;   // 100000
  const int E = in_sizes[1] / 2;     // 1600000
  const int nbk = (N + CB - 1) / CB; // 98
  const int Npad = (N + 63) & ~63;

  unsigned* ws = (unsigned*)d_ws;
  size_t o = 0;
  auto alloc = [&](size_t elems) { size_t p = o; o += (elems + 3) & ~(size_t)3; return p; };
  float*    norm_src = (float*)(ws + alloc(N));
  float*    norm_dst = (float*)(ws + alloc(N));
  unsigned* off      = ws + alloc(N + 1);
  unsigned* bCntD    = ws + alloc(128);   // bCntD,bCntS,curD,curS contiguous: one memset
  unsigned* bCntS    = ws + alloc(128);
  unsigned* curD     = ws + alloc(128);
  unsigned* curS     = ws + alloc(128);
  unsigned* bmask    = ws + alloc((size_t)4 * N);            // 1.6 MB dropout bitmask
  unsigned* pd       = ws + alloc(E);                        // 6.4 MB
  unsigned short* ps = (unsigned short*)(ws + alloc(E / 2)); // 3.2 MB
  int*      csr      = (int*)(ws + alloc(E));                // 6.4 MB
  unsigned* W1t32    = ws + alloc(128 * 128);
  unsigned* W2t32    = ws + alloc(48 * 64);
  unsigned short* h1 = (unsigned short*)(ws + alloc((size_t)N * NF1 / 2));
  unsigned* g64u     = ws + alloc((size_t)Npad * 32);        // 12.8 MB g64 rows
  unsigned short* g64 = (unsigned short*)g64u;

  hipMemsetAsync(bCntD, 0, 512 * sizeof(unsigned), stream);

  int wblk = (128 * 128 + 48 * 64 + 255) / 256;
  int mblk = (4 * N + 255) / 256;
  k_chist<<<256 + wblk, 256, 0, stream>>>(ei, E, nbk, bCntD, bCntS, W1, W2,
                                          W1t32, W2t32);
  k_cscatter<<<256, 256, 0, stream>>>(ei, E, bCntD, bCntS, curD, curS, pd, ps, nbk);
  k_fine<<<2 * nbk + mblk, 256, 0, stream>>>(bCntD, bCntS, pd, ps, off, norm_dst,
                                             norm_src, csr, N, E, nbk, bmask);
  k_gemm1<<<(N + 127) / 128, 256, 0, stream>>>(x, W1t32, norm_src, h1, N);
  k_gather1<<<(N + 31) / 32, 128, 0, stream>>>(off, csr, h1, norm_dst, norm_src,
                                               b1, bmask, W2t32, g64, N);
  k_gather2<<<((size_t)N * 64 + 127) / 128, 128, 0, stream>>>(
      off, csr, (const unsigned*)g64u, norm_dst, b2, out, N);
}